// Round 7
// baseline (76.670 us; speedup 1.0000x reference)
//
#include <hip/hip_runtime.h>
#include <hip/hip_bf16.h>
#include <stdint.h>

// ---------------------------------------------------------------------------
// out[b,t,a,:] = (state_in[b,t,a,:] @ readin[session[b]]) @ project
// Factored: W_b = readin[session[b]] @ project  (192x256), out_b = X_b @ W_b.
// k1 builds W_t[b][o][i] (bf16, K-major) in d_ws.
// k2: NO per-step barriers. B staged once per block in LDS (48KB,
// [kslot][row] conflict-free layout, one __syncthreads). A streamed
// global->reg per 16-row strip with depth-1 strip prefetch; full K=192
// per strip; stores fire-and-forget. 3 blocks/CU, waves fully decoupled.
// ---------------------------------------------------------------------------

typedef short    bf16x8 __attribute__((ext_vector_type(8)));
typedef float    f32x4  __attribute__((ext_vector_type(4)));
typedef uint32_t u32x4  __attribute__((ext_vector_type(4)));

#define NB    128   // batch
#define MPB   1024  // rows per batch = T*A
#define INF   192   // K of main GEMM
#define RDIM  64
#define OUTF  256

// round-to-nearest-even f32 -> bf16 bits (scalar path, used in k1)
__device__ __forceinline__ uint16_t f2bf(float f) {
    union { float f; uint32_t u; } v; v.f = f;
    return (uint16_t)((v.u + 0x7fffu + ((v.u >> 16) & 1u)) >> 16);
}
__device__ __forceinline__ uint32_t pack2(float a, float b) {
    return (uint32_t)f2bf(a) | ((uint32_t)f2bf(b) << 16);
}

// packed f32x8 -> bf16x8 via __float22bfloat162_rn (v_cvt_pk_bf16_f32)
__device__ __forceinline__ bf16x8 cvt8(f32x4 a, f32x4 b) {
    union { __hip_bfloat162 h2[4]; bf16x8 h; } r;
    r.h2[0] = __float22bfloat162_rn({a[0], a[1]});
    r.h2[1] = __float22bfloat162_rn({a[2], a[3]});
    r.h2[2] = __float22bfloat162_rn({b[0], b[1]});
    r.h2[3] = __float22bfloat162_rn({b[2], b[3]});
    return r.h;
}

// global -> LDS direct copy, 16B per lane. LDS dest must be wave-uniform base.
__device__ __forceinline__ void gl_lds16(const void* g, void* l) {
    auto gp = (const __attribute__((address_space(1))) uint32_t*)(uintptr_t)g;
    auto lp = (__attribute__((address_space(3))) uint32_t*)(uintptr_t)l;
    __builtin_amdgcn_global_load_lds(gp, lp, 16, 0, 0);
}

// ---------------------------------------------------------------------------
// k1: W_t[b][o][i] = sum_h project[h][o] * readin[session[b]][i][h]
// grid 256 = (b:128) x (o-half:2); block 256 thr (4 waves, 2x2 wave grid)
// (unchanged; proven correct, small cost)
// ---------------------------------------------------------------------------
__global__ __launch_bounds__(256) void k1_build_w(
    const float* __restrict__ readin,    // [512][192][64]
    const float* __restrict__ project,   // [64][256]
    const int*   __restrict__ session,   // [128]
    uint16_t*    __restrict__ Wt)        // [128][256][192] bf16 bits
{
    __shared__ uint16_t Rl[INF * 64];   // [i][h] bf16, XOR-swizzled, 24KB
    __shared__ uint16_t Pl[128 * 64];   // [o][h] bf16, XOR-swizzled, 16KB

    const int b  = blockIdx.x >> 1;
    const int oh = blockIdx.x & 1;
    const int t  = threadIdx.x;
    const float* Rg = readin + (size_t)session[b] * (INF * RDIM);

#pragma unroll
    for (int c = 0; c < 3; ++c) {
        int idx = c * 4096 + t * 16;       // linear into [192][64]
        int row = idx >> 6;
        int kg0 = (idx & 63) >> 3;
        f32x4 v0 = *(const f32x4*)(Rg + idx);
        f32x4 v1 = *(const f32x4*)(Rg + idx + 4);
        f32x4 v2 = *(const f32x4*)(Rg + idx + 8);
        f32x4 v3 = *(const f32x4*)(Rg + idx + 12);
        u32x4 d0, d1;
        d0[0] = pack2(v0[0], v0[1]); d0[1] = pack2(v0[2], v0[3]);
        d0[2] = pack2(v1[0], v1[1]); d0[3] = pack2(v1[2], v1[3]);
        d1[0] = pack2(v2[0], v2[1]); d1[1] = pack2(v2[2], v2[3]);
        d1[2] = pack2(v3[0], v3[1]); d1[3] = pack2(v3[2], v3[3]);
        *(u32x4*)&Rl[row * 64 + (((kg0    ) ^ (row & 7)) << 3)] = d0;
        *(u32x4*)&Rl[row * 64 + (((kg0 + 1) ^ (row & 7)) << 3)] = d1;
    }
    {
        int h  = t >> 2;
        int og = (t & 3) * 32;
        const float* Pg = project + (size_t)h * OUTF + oh * 128 + og;
#pragma unroll
        for (int q = 0; q < 8; ++q) {
            f32x4 v = *(const f32x4*)(Pg + q * 4);
#pragma unroll
            for (int e = 0; e < 4; ++e) {
                int o = og + q * 4 + e;
                Pl[o * 64 + (((h >> 3) ^ (o & 7)) << 3) + (h & 7)] = f2bf(v[e]);
            }
        }
    }
    __syncthreads();

    const int l  = t & 63, w = t >> 6;
    const int wm = w >> 1, wn = w & 1;
    const int lr = l & 15, lk = l >> 4;

    f32x4 acc[4][6];
#pragma unroll
    for (int m = 0; m < 4; ++m)
#pragma unroll
        for (int n = 0; n < 6; ++n) acc[m][n] = f32x4{0.f, 0.f, 0.f, 0.f};

#pragma unroll
    for (int kk = 0; kk < 2; ++kk) {
        int kg = kk * 4 + lk;
        bf16x8 a[4], bb[6];
#pragma unroll
        for (int m = 0; m < 4; ++m) {
            int row = wm * 64 + m * 16 + lr;
            a[m] = *(const bf16x8*)&Pl[row * 64 + ((kg ^ (row & 7)) << 3)];
        }
#pragma unroll
        for (int n = 0; n < 6; ++n) {
            int col = wn * 96 + n * 16 + lr;
            bb[n] = *(const bf16x8*)&Rl[col * 64 + ((kg ^ (col & 7)) << 3)];
        }
#pragma unroll
        for (int m = 0; m < 4; ++m)
#pragma unroll
            for (int n = 0; n < 6; ++n)
                acc[m][n] = __builtin_amdgcn_mfma_f32_16x16x32_bf16(
                    a[m], bb[n], acc[m][n], 0, 0, 0);
    }

    uint16_t* Wb = Wt + ((size_t)b * OUTF + oh * 128) * INF;
#pragma unroll
    for (int m = 0; m < 4; ++m) {
        int o = wm * 64 + m * 16 + lk * 4;
#pragma unroll
        for (int n = 0; n < 6; ++n) {
            int i = wn * 96 + n * 16 + lr;
#pragma unroll
            for (int j = 0; j < 4; ++j)
                Wb[(size_t)(o + j) * INF + i] = f2bf(acc[m][n][j]);
        }
    }
}

// ---------------------------------------------------------------------------
// k2: block = 256 thr (4 waves), tile M=256 x N=128, full K=192.
// Bs [kslot 0..23][row 0..127] 16B units = 48KB, staged once via gl_lds
// (source permuted), ONE __syncthreads. Conflict-free reads (verified R6).
// Each wave: 4 strips of 16 rows; per strip 12 global_load_dwordx4 (A, f32)
// -> cvt8 -> 48 MFMA vs B from LDS -> 32 stores. Depth-1 strip prefetch:
// cvt(s) frees the single pa buffer, then issue loads for s+1 (WAR safe,
// regions pinned with sched_barrier(0)); compiler emits counted vmcnt.
// Grid 1024 = b(128) x mt(4) x nt(2), bijective XCD swizzle (1024%8==0).
// ---------------------------------------------------------------------------
__global__ __launch_bounds__(256, 3) void k2_gemm(
    const float*    __restrict__ X,    // [128][1024][192]
    const uint16_t* __restrict__ Wt,   // [128][256][192] bf16
    float*          __restrict__ Y)    // [128][1024][256]
{
    __shared__ uint8_t Bs[24 * 128 * 16];   // 48 KB

    const int bid0 = blockIdx.x;
    const int bid  = ((bid0 & 7) << 7) | (bid0 >> 3);   // XCD swizzle
    const int b  = bid >> 3;
    const int mt = (bid >> 1) & 3;
    const int nt = bid & 1;
    const int t  = threadIdx.x, l = t & 63, w = t >> 6;
    const int lr = l & 15, lk = l >> 4;

    const float*    Xb = X  + ((size_t)b * MPB  + mt * 256) * INF;
    const uint16_t* Wb = Wt + ((size_t)b * OUTF + nt * 128) * INF;
    float*          Yb = Y  + ((size_t)b * MPB  + mt * 256) * OUTF + nt * 128;

    // ---- stage B once: 48 x 1KB chunks; wave w -> chunks w*12 .. w*12+11 ----
    // LDS unit i = c*64 + l  ->  kslot = i>>7 (0..23), row = i&127.
#pragma unroll
    for (int j = 0; j < 12; ++j) {
        int c     = w * 12 + j;
        int i     = c * 64 + l;
        int kslot = i >> 7;
        int row   = i & 127;
        gl_lds16(Wb + (size_t)row * INF + kslot * 8, &Bs[c * 1024]);
    }

    // ---- A strip geometry: wave w owns rows [w*64, w*64+64), strips s=0..3.
    // Lane covers row = w*64 + s*16 + lr, k = kk*32 + lk*8 (8 f32 = 2 x f32x4).
    const float* arow = Xb + (size_t)(w * 64 + lr) * INF + lk * 8;

    f32x4 pa[12];
#pragma unroll
    for (int kk = 0; kk < 6; ++kk) {            // issue strip 0
        const float* p = arow + kk * 32;
        pa[2 * kk]     = *(const f32x4*)(p);
        pa[2 * kk + 1] = *(const f32x4*)(p + 4);
    }

    __syncthreads();    // B ready (drains vmcnt once, prologue only)

#pragma unroll
    for (int s = 0; s < 4; ++s) {
        // convert current strip (compiler inserts the counted vmcnt wait)
        bf16x8 h[6];
#pragma unroll
        for (int kk = 0; kk < 6; ++kk)
            h[kk] = cvt8(pa[2 * kk], pa[2 * kk + 1]);
        __builtin_amdgcn_sched_barrier(0);
        // issue next strip into the (now consumed) pa buffer
        if (s < 3) {
#pragma unroll
            for (int kk = 0; kk < 6; ++kk) {
                const float* p = arow + (size_t)(s + 1) * (16 * INF) + kk * 32;
                pa[2 * kk]     = *(const f32x4*)(p);
                pa[2 * kk + 1] = *(const f32x4*)(p + 4);
            }
        }
        __builtin_amdgcn_sched_barrier(0);

        // compute 16(M) x 128(N) x 192(K)
        f32x4 acc[8];
#pragma unroll
        for (int n = 0; n < 8; ++n) acc[n] = f32x4{0.f, 0.f, 0.f, 0.f};
#pragma unroll
        for (int kk = 0; kk < 6; ++kk) {
            const int ko = (kk * 4 + lk) * 2048 + lr * 16;
#pragma unroll
            for (int n = 0; n < 8; ++n) {
                bf16x8 bfr = *(const bf16x8*)&Bs[ko + n * 256];
                acc[n] = __builtin_amdgcn_mfma_f32_16x16x32_bf16(
                    h[kk], bfr, acc[n], 0, 0, 0);
            }
        }

        // store strip: D row = lk*4+j, col = n*16+lr
        float* yr = Yb + (size_t)(w * 64 + s * 16 + lk * 4) * OUTF;
#pragma unroll
        for (int n = 0; n < 8; ++n)
#pragma unroll
            for (int j = 0; j < 4; ++j)
                yr[(size_t)j * OUTF + n * 16 + lr] = acc[n][j];
    }
}

extern "C" void kernel_launch(void* const* d_in, const int* in_sizes, int n_in,
                              void* d_out, int out_size, void* d_ws, size_t ws_size,
                              hipStream_t stream) {
    (void)in_sizes; (void)n_in; (void)out_size; (void)ws_size;
    const float* state   = (const float*)d_in[0];
    const int*   session = (const int*)  d_in[1];
    const float* readin  = (const float*)d_in[2];
    const float* project = (const float*)d_in[3];
    float*    out = (float*)d_out;
    uint16_t* Wt  = (uint16_t*)d_ws;   // 128*256*192*2 B = 12.6 MB scratch

    hipLaunchKernelGGL(k1_build_w, dim3(256), dim3(256), 0, stream,
                       readin, project, session, Wt);
    hipLaunchKernelGGL(k2_gemm, dim3(1024), dim3(256), 0, stream,
                       state, Wt, out);
}

// Round 8
// 51.254 us; speedup vs baseline: 1.4959x; 1.4959x over previous
//
#include <hip/hip_runtime.h>
#include <hip/hip_bf16.h>
#include <stdint.h>

// ---------------------------------------------------------------------------
// out[b,t,a,:] = (state_in[b,t,a,:] @ readin[session[b]]) @ project
// SINGLE fused kernel. Per block (b, mt, nt):
//   prologue: W panel (128 o x 192 i) = readin[s]^T @ project slice, computed
//     with MFMA from LDS-staged R,P and stored bf16 into LDS Bs[kslot][row].
//   main: A (X, f32) streamed per-wave-private via global_load_lds (2 bufs,
//     depth-2, counted per-wave vmcnt(4)); ZERO barriers in the main loop.
// LDS arena 80KB: Bs 48KB | A 4 waves x 2 x 4KB (prologue overlays R,P).
// ---------------------------------------------------------------------------

typedef short    bf16x8 __attribute__((ext_vector_type(8)));
typedef float    f32x4  __attribute__((ext_vector_type(4)));
typedef uint32_t u32x4  __attribute__((ext_vector_type(4)));

#define NB    128   // batch
#define MPB   1024  // rows per batch = T*A
#define INF   192   // K of main GEMM
#define RDIM  64
#define OUTF  256

#define WAIT_VM4()   asm volatile("s_waitcnt vmcnt(4)" ::: "memory")
#define WAIT_VM0()   asm volatile("s_waitcnt vmcnt(0)" ::: "memory")
#define WAIT_LGKM0() asm volatile("s_waitcnt lgkmcnt(0)" ::: "memory")

// round-to-nearest-even f32 -> bf16 bits
__device__ __forceinline__ uint16_t f2bf(float f) {
    union { float f; uint32_t u; } v; v.f = f;
    return (uint16_t)((v.u + 0x7fffu + ((v.u >> 16) & 1u)) >> 16);
}
__device__ __forceinline__ uint32_t pack2(float a, float b) {
    return (uint32_t)f2bf(a) | ((uint32_t)f2bf(b) << 16);
}
// packed f32x8 -> bf16x8 via v_cvt_pk_bf16_f32
__device__ __forceinline__ bf16x8 cvt8(f32x4 a, f32x4 b) {
    union { __hip_bfloat162 h2[4]; bf16x8 h; } r;
    r.h2[0] = __float22bfloat162_rn({a[0], a[1]});
    r.h2[1] = __float22bfloat162_rn({a[2], a[3]});
    r.h2[2] = __float22bfloat162_rn({b[0], b[1]});
    r.h2[3] = __float22bfloat162_rn({b[2], b[3]});
    return r.h;
}
// global -> LDS direct copy, 16B/lane; LDS dest wave-uniform base.
__device__ __forceinline__ void gl_lds16(const void* g, void* l) {
    auto gp = (const __attribute__((address_space(1))) uint32_t*)(uintptr_t)g;
    auto lp = (__attribute__((address_space(3))) uint32_t*)(uintptr_t)l;
    __builtin_amdgcn_global_load_lds(gp, lp, 16, 0, 0);
}

// ---------------------------------------------------------------------------
// fused: grid 2048 = b(128) x mt(8) x nt(2), XCD-swizzled; block 256 thr.
// ---------------------------------------------------------------------------
__global__ __launch_bounds__(256, 2) void fused_gemm(
    const float* __restrict__ X,        // [128][1024][192]
    const int*   __restrict__ session,  // [128]
    const float* __restrict__ readin,   // [512][192][64]
    const float* __restrict__ project,  // [64][256]
    float*       __restrict__ Y)        // [128][1024][256]
{
    __shared__ __attribute__((aligned(16))) uint8_t arena[81920];

    const int bid0 = blockIdx.x;
    const int bid  = ((bid0 & 7) << 8) | (bid0 >> 3);   // bijective XCD swizzle
    const int b  = bid >> 4;
    const int mt = (bid >> 1) & 7;
    const int nt = bid & 1;
    const int t  = threadIdx.x, l = t & 63, w = t >> 6;
    const int lr = l & 15, lk = l >> 4;

    const float* Xb = X + ((size_t)b * MPB + mt * 128) * INF;
    float*       Yb = Y + ((size_t)b * MPB + mt * 128) * OUTF + nt * 128;

    // ================= prologue: W panel -> Bs (bf16, [kslot][row]) =========
    {
        uint16_t* Rl = (uint16_t*)arena;             // [192][64] swz, 24KB
        uint16_t* Pl = (uint16_t*)(arena + 49152);   // [128][64] swz, 16KB
        const float* Rg = readin + (size_t)session[b] * (INF * RDIM);

        // stage R (192x64 f32 -> bf16, XOR-swizzled) — k1-verbatim
#pragma unroll
        for (int c = 0; c < 3; ++c) {
            int idx = c * 4096 + t * 16;
            int row = idx >> 6;
            int kg0 = (idx & 63) >> 3;
            f32x4 v0 = *(const f32x4*)(Rg + idx);
            f32x4 v1 = *(const f32x4*)(Rg + idx + 4);
            f32x4 v2 = *(const f32x4*)(Rg + idx + 8);
            f32x4 v3 = *(const f32x4*)(Rg + idx + 12);
            u32x4 d0, d1;
            d0[0] = pack2(v0[0], v0[1]); d0[1] = pack2(v0[2], v0[3]);
            d0[2] = pack2(v1[0], v1[1]); d0[3] = pack2(v1[2], v1[3]);
            d1[0] = pack2(v2[0], v2[1]); d1[1] = pack2(v2[2], v2[3]);
            d1[2] = pack2(v3[0], v3[1]); d1[3] = pack2(v3[2], v3[3]);
            *(u32x4*)&Rl[row * 64 + (((kg0    ) ^ (row & 7)) << 3)] = d0;
            *(u32x4*)&Rl[row * 64 + (((kg0 + 1) ^ (row & 7)) << 3)] = d1;
        }
        // stage P^T slice (o = nt*128 .. +128)
        {
            int h  = t >> 2;
            int og = (t & 3) * 32;
            const float* Pg = project + (size_t)h * OUTF + nt * 128 + og;
#pragma unroll
            for (int q = 0; q < 8; ++q) {
                f32x4 v = *(const f32x4*)(Pg + q * 4);
#pragma unroll
                for (int e = 0; e < 4; ++e) {
                    int o = og + q * 4 + e;
                    Pl[o * 64 + (((h >> 3) ^ (o & 7)) << 3) + (h & 7)] = f2bf(v[e]);
                }
            }
        }
        __syncthreads();

        const int wm = w >> 1, wn = w & 1;
        f32x4 acc[4][6];
#pragma unroll
        for (int m = 0; m < 4; ++m)
#pragma unroll
            for (int n = 0; n < 6; ++n) acc[m][n] = f32x4{0.f, 0.f, 0.f, 0.f};

#pragma unroll
        for (int kk = 0; kk < 2; ++kk) {
            int kg = kk * 4 + lk;
            bf16x8 a[4], bb[6];
#pragma unroll
            for (int m = 0; m < 4; ++m) {
                int row = wm * 64 + m * 16 + lr;
                a[m] = *(const bf16x8*)&Pl[row * 64 + ((kg ^ (row & 7)) << 3)];
            }
#pragma unroll
            for (int n = 0; n < 6; ++n) {
                int col = wn * 96 + n * 16 + lr;
                bb[n] = *(const bf16x8*)&Rl[col * 64 + ((kg ^ (col & 7)) << 3)];
            }
#pragma unroll
            for (int m = 0; m < 4; ++m)
#pragma unroll
                for (int n = 0; n < 6; ++n)
                    acc[m][n] = __builtin_amdgcn_mfma_f32_16x16x32_bf16(
                        a[m], bb[n], acc[m][n], 0, 0, 0);
        }
        __syncthreads();   // all Rl/Pl reads complete before overwrite

        // store W frags bf16 into Bs[kslot=i>>3][row=o] (overwrites Rl region)
        uint16_t* Bs16 = (uint16_t*)arena;
#pragma unroll
        for (int m = 0; m < 4; ++m) {
            int o0 = wm * 64 + m * 16 + lk * 4;
#pragma unroll
            for (int n = 0; n < 6; ++n) {
                int i = wn * 96 + n * 16 + lr;
#pragma unroll
                for (int j = 0; j < 4; ++j)
                    Bs16[((i >> 3) * 128 + (o0 + j)) * 8 + (i & 7)]
                        = f2bf(acc[m][n][j]);
            }
        }
        __syncthreads();   // W panel ready; Pl/A-region free
    }

    // ================= main: zero barriers ==================================
    // A wave-private: wave w owns rows w*32 .. +32. LDS [row 0..31][kq^row&7]
    // 16B units, 4KB per buf, 2 bufs. Source pre-swizzled (row-contiguous).
    uint8_t* Ab = arena + 49152 + w * 8192;
    const float* Aw = Xb + (size_t)(w * 32) * INF;

    int asrc[4];
#pragma unroll
    for (int c = 0; c < 4; ++c) {
        int i   = c * 64 + l;
        int row = i >> 3;                  // 0..31
        int kq  = (i & 7) ^ (row & 7);     // pre-swizzled source quad
        asrc[c] = row * INF + kq * 4;
    }
    auto stage = [&](int kk, int buf) {
#pragma unroll
        for (int c = 0; c < 4; ++c)
            gl_lds16(Aw + asrc[c] + kk * 32, Ab + buf * 4096 + c * 1024);
    };

    stage(0, 0);
    stage(1, 1);

    f32x4 acc[2][8];
#pragma unroll
    for (int m = 0; m < 2; ++m)
#pragma unroll
        for (int n = 0; n < 8; ++n) acc[m][n] = f32x4{0.f, 0.f, 0.f, 0.f};

    const int a0s = ((2 * lk)     ^ (lr & 7)) << 4;   // read-side swizzle
    const int a1s = ((2 * lk + 1) ^ (lr & 7)) << 4;

#pragma unroll
    for (int kk = 0; kk < 6; ++kk) {
        if (kk < 5) { WAIT_VM4(); } else { WAIT_VM0(); }   // own stage kk done
        __builtin_amdgcn_sched_barrier(0);

        const uint8_t* Abuf = Ab + (kk & 1) * 4096;
        bf16x8 af[2], bfr[8];
#pragma unroll
        for (int m = 0; m < 2; ++m) {
            const uint8_t* p = Abuf + (m * 16 + lr) * 128;
            f32x4 lo = *(const f32x4*)(p + a0s);
            f32x4 hi = *(const f32x4*)(p + a1s);
            af[m] = cvt8(lo, hi);
        }
#pragma unroll
        for (int n = 0; n < 8; ++n)
            bfr[n] = *(const bf16x8*)(arena
                        + (((kk * 4 + lk) * 128 + n * 16 + lr) << 4));

        WAIT_LGKM0();                       // buf reads retired before reuse
        __builtin_amdgcn_sched_barrier(0);
        if (kk < 4) stage(kk + 2, kk & 1);  // fire-and-forget, depth-2

#pragma unroll
        for (int m = 0; m < 2; ++m)
#pragma unroll
            for (int n = 0; n < 8; ++n)
                acc[m][n] = __builtin_amdgcn_mfma_f32_16x16x32_bf16(
                    af[m], bfr[n], acc[m][n], 0, 0, 0);
    }

    // epilogue: D row=(lane>>4)*4+j, col=lane&15
#pragma unroll
    for (int m = 0; m < 2; ++m) {
        int r0 = w * 32 + m * 16 + lk * 4;
#pragma unroll
        for (int n = 0; n < 8; ++n) {
            int c0 = n * 16 + lr;
#pragma unroll
            for (int j = 0; j < 4; ++j)
                Yb[(size_t)(r0 + j) * OUTF + c0] = acc[m][n][j];
        }
    }
}

extern "C" void kernel_launch(void* const* d_in, const int* in_sizes, int n_in,
                              void* d_out, int out_size, void* d_ws, size_t ws_size,
                              hipStream_t stream) {
    (void)in_sizes; (void)n_in; (void)out_size; (void)d_ws; (void)ws_size;
    const float* state   = (const float*)d_in[0];
    const int*   session = (const int*)  d_in[1];
    const float* readin  = (const float*)d_in[2];
    const float* project = (const float*)d_in[3];
    float*       out     = (float*)d_out;

    hipLaunchKernelGGL(fused_gemm, dim3(2048), dim3(256), 0, stream,
                       state, session, readin, project, out);
}